// Round 7
// baseline (94.759 us; speedup 1.0000x reference)
//
#include <hip/hip_runtime.h>
#include <hip/hip_bf16.h>
#include <stdint.h>

#define THRESH_FACTOR 0.05f

typedef __attribute__((ext_vector_type(8))) short short8;
typedef __attribute__((ext_vector_type(16))) float f32x16;

__device__ inline unsigned int bfbits(float f) {
    unsigned int u = __float_as_uint(f);
    return (u + 0x7FFFu + ((u >> 16) & 1u)) >> 16;   // RNE bf16 bits
}

// Chunk swizzle within each 8-chunk (64-elem) group; achieves the 4-lane/bank
// floor for 32-distinct-row b128 reads (measured: exactly 4 cyc/read, the
// 512B/128B-per-cy bandwidth floor — not improvable by any permutation).
__device__ inline int swz_row(int r) { return (r & 7) ^ ((r >> 3) & 7); }

// ---------------- Kernel 1: per-row ternary quantization -----------------
__global__ void __launch_bounds__(256) quant_tern(
        const float* __restrict__ W, unsigned short* __restrict__ Wq,
        float* __restrict__ scale, int IN)
{
    const int row = blockIdx.x;
    const int tid = threadIdx.x;
    const int lane = tid & 63;
    const int wid = tid >> 6;
    const float4* wr4 = (const float4*)(W + (size_t)row * IN);
    const int n4 = IN >> 2;

    float s = 0.f;
    for (int i = tid; i < n4; i += 256) {
        float4 v = wr4[i];
        s += fabsf(v.x) + fabsf(v.y) + fabsf(v.z) + fabsf(v.w);
    }
    #pragma unroll
    for (int off = 32; off; off >>= 1) s += __shfl_down(s, off);
    __shared__ float redA[4], redB[4];
    if (lane == 0) redA[wid] = s;
    __syncthreads();
    const float delta = THRESH_FACTOR * (redA[0] + redA[1] + redA[2] + redA[3]) / (float)IN;
    __syncthreads();   // all delta-reads done before redA reuse

    const int sr = swz_row(row);
    float ks = 0.f, kn = 0.f;
    uint4* out16 = (uint4*)(Wq + (size_t)row * IN);   // 16B chunks
    const int n8 = IN >> 3;                            // chunks per row
    for (int i = tid; i < n8; i += 256) {
        float4 v0 = wr4[2 * i], v1 = wr4[2 * i + 1];
        float vs[8] = {v0.x, v0.y, v0.z, v0.w, v1.x, v1.y, v1.z, v1.w};
        unsigned int h[8];
        #pragma unroll
        for (int j = 0; j < 8; ++j) {
            float a = fabsf(vs[j]);
            unsigned int u = __float_as_uint(vs[j]);
            if (a > delta) { ks += a; kn += 1.f; h[j] = 0x3F80u | ((u >> 16) & 0x8000u); }
            else h[j] = 0u;
        }
        uint4 o;
        o.x = h[0] | (h[1] << 16);
        o.y = h[2] | (h[3] << 16);
        o.z = h[4] | (h[5] << 16);
        o.w = h[6] | (h[7] << 16);
        const int oc = (i & ~7) | ((i & 7) ^ sr);   // chunk swizzle
        out16[oc] = o;
    }
    #pragma unroll
    for (int off = 32; off; off >>= 1) { ks += __shfl_down(ks, off); kn += __shfl_down(kn, off); }
    if (lane == 0) { redA[wid] = ks; redB[wid] = kn; }
    __syncthreads();
    if (tid == 0) {
        float tks = redA[0] + redA[1] + redA[2] + redA[3];
        float tkn = redB[0] + redB[1] + redB[2] + redB[3];
        scale[row] = tks / fmaxf(tkn, 1.f);
    }
}

// ---------------- Kernel 2: cast x (f32) -> bf16, chunk-swizzled -----------
__global__ void __launch_bounds__(256) cast_x(
        const float* __restrict__ X, unsigned short* __restrict__ Xb,
        int n16, int cpr)   // n16 = total 16B chunks, cpr = chunks per row (IN/8)
{
    int idx = blockIdx.x * blockDim.x + threadIdx.x;
    int stride = gridDim.x * blockDim.x;
    const float4* x4 = (const float4*)X;
    uint4* o16 = (uint4*)Xb;
    for (int i = idx; i < n16; i += stride) {
        int m = i / cpr;                    // source row
        float4 a = x4[2 * i], b = x4[2 * i + 1];
        uint4 o;
        o.x = bfbits(a.x) | (bfbits(a.y) << 16);
        o.y = bfbits(a.z) | (bfbits(a.w) << 16);
        o.z = bfbits(b.x) | (bfbits(b.y) << 16);
        o.w = bfbits(b.z) | (bfbits(b.w) << 16);
        const int oc = (i & ~7) | ((i & 7) ^ swz_row(m));   // chunk swizzle
        o16[oc] = o;
    }
}

// ---------------- Kernel 3: C = bias (broadcast init for atomic merge) -----
__global__ void __launch_bounds__(256) init_bias(
        const float* __restrict__ bias, float* __restrict__ C, int n4cols, int total4)
{
    int idx = blockIdx.x * blockDim.x + threadIdx.x;
    int stride = gridDim.x * blockDim.x;
    const float4* b4 = (const float4*)bias;
    float4* c4 = (float4*)C;
    for (int i = idx; i < total4; i += stride)
        c4[i] = b4[i & (n4cols - 1)];
}

// ---------------- Kernel 4: bf16 MFMA GEMM, split-K=2, atomic merge --------
// Grid 512 = 32 mtiles x 8 ntiles x 2 K-halves -> 2 blocks/CU (two independent
// barrier domains per CU fill each other's stage/barrier bubbles).
// Block: 256 threads = 4 waves (2x2), wave tile 64x64 = 2x2 frags of 32x32x16.
// BK=64, double-buffered LDS (64 KB), depth-2 counted-vmcnt pipeline.
// Epilogue: atomicAdd(C, acc*scale[col]) onto bias-initialized C.
#define BM 128
#define BN 128
#define BK 64
#define THREADS 256

__global__ void __launch_bounds__(256, 2) gemm_tern(
        const unsigned short* __restrict__ Xb,   // [M][K] bf16 bits, swizzled
        const unsigned short* __restrict__ Wq,   // [N][K] bf16 bits, swizzled
        const float* __restrict__ scale,         // [N]
        float* __restrict__ C,                   // [M][N] f32, pre-set to bias
        int M, int N, int K)
{
    __shared__ __attribute__((aligned(16))) unsigned short As[2][BM * BK]; // 2x16KB
    __shared__ __attribute__((aligned(16))) unsigned short Bs[2][BN * BK]; // 2x16KB

    const int tid    = threadIdx.x;
    const int lane   = tid & 63;
    const int lane31 = lane & 31;
    const int khalf  = lane >> 5;
    const int wid    = tid >> 6;   // 0..3
    const int wr     = wid >> 1;   // 0..1 (M)
    const int wc     = wid & 1;    // 0..1 (N)

    // XCD decode: XCD x handles n-tile x; within an XCD chunk, both K-halves
    // of consecutive m-tiles (B n-panel = 1 MB stays hot in that XCD's L2).
    const int bid     = blockIdx.x;
    const int logical = (bid & 7) * 64 + (bid >> 3);   // 0..511
    const int ntile   = logical >> 6;                  // 0..7
    const int rem     = logical & 63;
    const int sk      = rem >> 5;                      // K-half 0/1
    const int mtile   = rem & 31;                      // 0..31
    const int bm0 = mtile * BM;
    const int bn0 = ntile * BN;
    const int km0 = sk * (K >> 1);

    f32x16 acc[2][2];
    #pragma unroll
    for (int m = 0; m < 2; ++m)
        #pragma unroll
        for (int n = 0; n < 2; ++n)
            #pragma unroll
            for (int r = 0; r < 16; ++r)
                acc[m][n][r] = 0.f;

    const unsigned short* Ag = Xb + (size_t)bm0 * K + km0;
    const unsigned short* Bg = Wq + (size_t)bn0 * K + km0;

    // staging: each tile = 128 rows x 8 chunks(16B) per matrix; 8 calls/thread
    // call j (j<4: A, j>=4: B): row = (j&3)*32 + (tid>>3), pos = tid&7
    const int pos    = tid & 7;
    const int rbase  = tid >> 3;            // 0..31
    const int ldsoff = (tid & ~63) * 8;     // wave-uniform element base

    #define STAGE(buf, t)                                                          \
        do {                                                                       \
            _Pragma("unroll")                                                      \
            for (int j = 0; j < 4; ++j) {                                          \
                __builtin_amdgcn_global_load_lds(                                  \
                    (const __attribute__((address_space(1))) unsigned int*)        \
                        (Ag + (size_t)(j * 32 + rbase) * K + (t) * 64 + pos * 8),  \
                    (__attribute__((address_space(3))) unsigned int*)              \
                        (&As[buf][j * 2048 + ldsoff]),                             \
                    16, 0, 0);                                                     \
            }                                                                      \
            _Pragma("unroll")                                                      \
            for (int j = 0; j < 4; ++j) {                                          \
                __builtin_amdgcn_global_load_lds(                                  \
                    (const __attribute__((address_space(1))) unsigned int*)        \
                        (Bg + (size_t)(j * 32 + rbase) * K + (t) * 64 + pos * 8),  \
                    (__attribute__((address_space(3))) unsigned int*)              \
                        (&Bs[buf][j * 2048 + ldsoff]),                             \
                    16, 0, 0);                                                     \
            }                                                                      \
        } while (0)

    const int NT = (K >> 1) / BK;    // 32

    const int rA0 = wr * 64 + lane31, rA1 = rA0 + 32;
    const int rB0 = wc * 64 + lane31, rB1 = rB0 + 32;
    const int sA0 = swz_row(rA0), sA1 = swz_row(rA1);
    const int sB0 = swz_row(rB0), sB1 = swz_row(rB1);

    STAGE(0, 0);
    int cur = 0;

    for (int t = 0; t < NT; ++t) {
        if (t + 1 < NT) {
            STAGE(cur ^ 1, t + 1);
            asm volatile("s_waitcnt vmcnt(8)" ::: "memory");  // my tile-t loads done
        } else {
            asm volatile("s_waitcnt vmcnt(0)" ::: "memory");
        }
        __builtin_amdgcn_s_barrier();                         // tile t staged (all)

        __builtin_amdgcn_s_setprio(1);
        #pragma unroll
        for (int kk = 0; kk < 4; ++kk) {
            const int c = kk * 2 + khalf;    // logical chunk 0..7
            short8 a0 = *(const short8*)&As[cur][rA0 * BK + ((c ^ sA0) * 8)];
            short8 a1 = *(const short8*)&As[cur][rA1 * BK + ((c ^ sA1) * 8)];
            short8 b0 = *(const short8*)&Bs[cur][rB0 * BK + ((c ^ sB0) * 8)];
            short8 b1 = *(const short8*)&Bs[cur][rB1 * BK + ((c ^ sB1) * 8)];
            acc[0][0] = __builtin_amdgcn_mfma_f32_32x32x16_bf16(a0, b0, acc[0][0], 0, 0, 0);
            acc[0][1] = __builtin_amdgcn_mfma_f32_32x32x16_bf16(a0, b1, acc[0][1], 0, 0, 0);
            acc[1][0] = __builtin_amdgcn_mfma_f32_32x32x16_bf16(a1, b0, acc[1][0], 0, 0, 0);
            acc[1][1] = __builtin_amdgcn_mfma_f32_32x32x16_bf16(a1, b1, acc[1][1], 0, 0, 0);
        }
        __builtin_amdgcn_s_setprio(0);
        __builtin_amdgcn_s_barrier();    // all reads of buf `cur` done before restage
        cur ^= 1;
    }

    // ---- epilogue: atomic merge of this K-half, scaled per column ----
    #pragma unroll
    for (int n = 0; n < 2; ++n) {
        int col = bn0 + wc * 64 + n * 32 + lane31;
        float sc = scale[col];
        #pragma unroll
        for (int m = 0; m < 2; ++m) {
            int rowbase = bm0 + wr * 64 + m * 32 + 4 * khalf;
            #pragma unroll
            for (int r = 0; r < 16; ++r) {
                int row = rowbase + (r & 3) + 8 * (r >> 2);
                atomicAdd(&C[(size_t)row * N + col], acc[m][n][r] * sc);
            }
        }
    }
    #undef STAGE
}

extern "C" void kernel_launch(void* const* d_in, const int* in_sizes, int n_in,
                              void* d_out, int out_size, void* d_ws, size_t ws_size,
                              hipStream_t stream)
{
    const float* x    = (const float*)d_in[0];
    const float* w    = (const float*)d_in[1];
    const float* bias = (const float*)d_in[2];
    float* out = (float*)d_out;

    const int OUT = in_sizes[2];            // 1024
    const int IN  = in_sizes[1] / OUT;      // 4096
    const int B   = in_sizes[0] / IN;       // 4096

    // workspace layout: x_bf16 [B*IN] | w_tern_bf16 [OUT*IN] | scale [OUT]
    unsigned short* Xb = (unsigned short*)d_ws;
    unsigned short* Wq = Xb + (size_t)B * IN;
    float* scale = (float*)(Wq + (size_t)OUT * IN);

    quant_tern<<<OUT, 256, 0, stream>>>(w, Wq, scale, IN);
    cast_x<<<2048, 256, 0, stream>>>(x, Xb, (B * IN) / 8, IN / 8);
    init_bias<<<2048, 256, 0, stream>>>(bias, out, OUT / 4, (B * OUT) / 4);
    gemm_tern<<<512, THREADS, 0, stream>>>(Xb, Wq, scale, out, B, OUT, IN);
}

// Round 8
// 71.752 us; speedup vs baseline: 1.3206x; 1.3206x over previous
//
#include <hip/hip_runtime.h>
#include <hip/hip_bf16.h>
#include <stdint.h>

#define THRESH_FACTOR 0.05f

typedef __attribute__((ext_vector_type(8))) short short8;
typedef __attribute__((ext_vector_type(16))) float f32x16;

__device__ inline unsigned int bfbits(float f) {
    unsigned int u = __float_as_uint(f);
    return (u + 0x7FFFu + ((u >> 16) & 1u)) >> 16;   // RNE bf16 bits
}

// Chunk swizzle within each 8-chunk (64-elem) group; achieves the 4-lane/bank
// floor for 32-distinct-row b128 reads (R6: exactly 4 cyc/read = 512B/128Bcy).
__device__ inline int swz_row(int r) { return (r & 7) ^ ((r >> 3) & 7); }

// ---------------- Kernel 1: per-row ternary quantization -----------------
__global__ void __launch_bounds__(256) quant_tern(
        const float* __restrict__ W, unsigned short* __restrict__ Wq,
        float* __restrict__ scale, int IN)
{
    const int row = blockIdx.x;
    const int tid = threadIdx.x;
    const int lane = tid & 63;
    const int wid = tid >> 6;
    const float4* wr4 = (const float4*)(W + (size_t)row * IN);
    const int n4 = IN >> 2;

    float s = 0.f;
    for (int i = tid; i < n4; i += 256) {
        float4 v = wr4[i];
        s += fabsf(v.x) + fabsf(v.y) + fabsf(v.z) + fabsf(v.w);
    }
    #pragma unroll
    for (int off = 32; off; off >>= 1) s += __shfl_down(s, off);
    __shared__ float redA[4], redB[4];
    if (lane == 0) redA[wid] = s;
    __syncthreads();
    const float delta = THRESH_FACTOR * (redA[0] + redA[1] + redA[2] + redA[3]) / (float)IN;
    __syncthreads();   // all delta-reads done before redA reuse

    const int sr = swz_row(row);
    float ks = 0.f, kn = 0.f;
    uint4* out16 = (uint4*)(Wq + (size_t)row * IN);   // 16B chunks
    const int n8 = IN >> 3;                            // chunks per row
    for (int i = tid; i < n8; i += 256) {
        float4 v0 = wr4[2 * i], v1 = wr4[2 * i + 1];
        float vs[8] = {v0.x, v0.y, v0.z, v0.w, v1.x, v1.y, v1.z, v1.w};
        unsigned int h[8];
        #pragma unroll
        for (int j = 0; j < 8; ++j) {
            float a = fabsf(vs[j]);
            unsigned int u = __float_as_uint(vs[j]);
            if (a > delta) { ks += a; kn += 1.f; h[j] = 0x3F80u | ((u >> 16) & 0x8000u); }
            else h[j] = 0u;
        }
        uint4 o;
        o.x = h[0] | (h[1] << 16);
        o.y = h[2] | (h[3] << 16);
        o.z = h[4] | (h[5] << 16);
        o.w = h[6] | (h[7] << 16);
        const int oc = (i & ~7) | ((i & 7) ^ sr);   // chunk swizzle
        out16[oc] = o;
    }
    #pragma unroll
    for (int off = 32; off; off >>= 1) { ks += __shfl_down(ks, off); kn += __shfl_down(kn, off); }
    if (lane == 0) { redA[wid] = ks; redB[wid] = kn; }
    __syncthreads();
    if (tid == 0) {
        float tks = redA[0] + redA[1] + redA[2] + redA[3];
        float tkn = redB[0] + redB[1] + redB[2] + redB[3];
        scale[row] = tks / fmaxf(tkn, 1.f);
    }
}

// ---------------- Kernel 2: cast x (f32) -> bf16, chunk-swizzled -----------
__global__ void __launch_bounds__(256) cast_x(
        const float* __restrict__ X, unsigned short* __restrict__ Xb,
        int n16, int cpr)   // n16 = total 16B chunks, cpr = chunks per row (IN/8)
{
    int idx = blockIdx.x * blockDim.x + threadIdx.x;
    int stride = gridDim.x * blockDim.x;
    const float4* x4 = (const float4*)X;
    uint4* o16 = (uint4*)Xb;
    for (int i = idx; i < n16; i += stride) {
        int m = i / cpr;                    // source row
        float4 a = x4[2 * i], b = x4[2 * i + 1];
        uint4 o;
        o.x = bfbits(a.x) | (bfbits(a.y) << 16);
        o.y = bfbits(a.z) | (bfbits(a.w) << 16);
        o.z = bfbits(b.x) | (bfbits(b.y) << 16);
        o.w = bfbits(b.z) | (bfbits(b.w) << 16);
        const int oc = (i & ~7) | ((i & 7) ^ swz_row(m));   // chunk swizzle
        o16[oc] = o;
    }
}

// ---------------- Kernel 3: bf16 MFMA GEMM, 16-wave blocks -----------------
// BM=BN=128, BK=128. 1024 threads = 16 waves: 4 spatial (2x2, wave 64x64,
// 2x2 frags of 32x32x16, reads:MFMA=1:1) x 4 K-groups (kg owns K=32 of each
// step). 4 waves/SIMD for latency hiding (R6 ran 2/SIMD, latency-bound).
// Double-buffered LDS 128KB, depth-2 counted-vmcnt pipeline. kg-merge via
// aliased LDS, 2 rounds. Epilogue: C = acc*scale[col] + bias[col].
#define BM 128
#define BN 128
#define BK 128
#define THREADS 1024

__global__ void __launch_bounds__(1024, 4) gemm_tern(
        const unsigned short* __restrict__ Xb,   // [M][K] bf16 bits, swizzled
        const unsigned short* __restrict__ Wq,   // [N][K] bf16 bits, swizzled
        const float* __restrict__ scale,         // [N]
        const float* __restrict__ bias,          // [N]
        float* __restrict__ C,                   // [M][N] f32
        int M, int N, int K)
{
    __shared__ __attribute__((aligned(16))) unsigned short AsBs[2][2][BM * BK]; // 128 KB
    #define AS(b) (AsBs[b][0])
    #define BS(b) (AsBs[b][1])

    const int tid    = threadIdx.x;
    const int lane   = tid & 63;
    const int lane31 = lane & 31;
    const int khalf  = lane >> 5;
    const int wid    = tid >> 6;   // 0..15
    const int kg     = wid >> 2;   // K-group 0..3 (owns k[kg*32, kg*32+32))
    const int wq     = wid & 3;    // spatial wave id
    const int wr     = wq >> 1;    // 0..1 (M)
    const int wc     = wq & 1;     // 0..1 (N)

    // XCD-aware bijective swizzle (nwg=256, divisible by 8)
    const int nwg = gridDim.x;
    const int bid = blockIdx.x;
    const int swz = (bid & 7) * (nwg >> 3) + (bid >> 3);
    const int ntn = N / BN;                   // 8
    const int bm0 = (swz / ntn) * BM;
    const int bn0 = (swz % ntn) * BN;

    f32x16 acc[2][2];
    #pragma unroll
    for (int m = 0; m < 2; ++m)
        #pragma unroll
        for (int n = 0; n < 2; ++n)
            #pragma unroll
            for (int r = 0; r < 16; ++r)
                acc[m][n][r] = 0.f;

    const unsigned short* Ag = Xb + (size_t)bm0 * K;
    const unsigned short* Bg = Wq + (size_t)bn0 * K;

    // staging: tile = 128 rows x 16 chunks(16B) = 2048 slots per matrix;
    // 1024 threads -> 2 A-loads + 2 B-loads per thread. Linear dest.
    const int schk   = tid & 15;
    const int srow0  = tid >> 4;            // slot c*1024+tid -> row c*64 + (tid>>4)
    const int ldsel0 = (tid & ~63) * 8;     // element base for call c (+c*8192)

    #define STAGE(buf, t)                                                          \
        do {                                                                       \
            _Pragma("unroll")                                                      \
            for (int c = 0; c < 2; ++c) {                                          \
                __builtin_amdgcn_global_load_lds(                                  \
                    (const __attribute__((address_space(1))) unsigned int*)        \
                        (Ag + (size_t)(c * 64 + srow0) * K + (t) * 128 + schk * 8),\
                    (__attribute__((address_space(3))) unsigned int*)              \
                        (&AS(buf)[c * 8192 + ldsel0]),                             \
                    16, 0, 0);                                                     \
                __builtin_amdgcn_global_load_lds(                                  \
                    (const __attribute__((address_space(1))) unsigned int*)        \
                        (Bg + (size_t)(c * 64 + srow0) * K + (t) * 128 + schk * 8),\
                    (__attribute__((address_space(3))) unsigned int*)              \
                        (&BS(buf)[c * 8192 + ldsel0]),                             \
                    16, 0, 0);                                                     \
            }                                                                      \
        } while (0)

    const int NT = K / BK;    // 32

    const int rA0 = wr * 64 + lane31, rA1 = rA0 + 32;
    const int rB0 = wc * 64 + lane31, rB1 = rB0 + 32;
    const int sA0 = swz_row(rA0), sA1 = swz_row(rA1);
    const int sB0 = swz_row(rB0), sB1 = swz_row(rB1);

    STAGE(0, 0);
    int cur = 0;

    for (int t = 0; t < NT; ++t) {
        if (t + 1 < NT) {
            STAGE(cur ^ 1, t + 1);
            asm volatile("s_waitcnt vmcnt(4)" ::: "memory");  // my tile-t loads done
        } else {
            asm volatile("s_waitcnt vmcnt(0)" ::: "memory");
        }
        __builtin_amdgcn_s_barrier();                         // tile t staged (all)

        __builtin_amdgcn_s_setprio(1);
        #pragma unroll
        for (int kk = 0; kk < 2; ++kk) {
            // logical chunk within 16: kg*4 + kk*2 + khalf; swizzle acts on low 3 bits
            const int c7 = (kg & 1) * 4 + kk * 2 + khalf;
            const int chi = (kg >> 1) * 8;
            short8 a0 = *(const short8*)&AS(cur)[rA0 * BK + (chi + (c7 ^ sA0)) * 8];
            short8 a1 = *(const short8*)&AS(cur)[rA1 * BK + (chi + (c7 ^ sA1)) * 8];
            short8 b0 = *(const short8*)&BS(cur)[rB0 * BK + (chi + (c7 ^ sB0)) * 8];
            short8 b1 = *(const short8*)&BS(cur)[rB1 * BK + (chi + (c7 ^ sB1)) * 8];
            acc[0][0] = __builtin_amdgcn_mfma_f32_32x32x16_bf16(a0, b0, acc[0][0], 0, 0, 0);
            acc[0][1] = __builtin_amdgcn_mfma_f32_32x32x16_bf16(a0, b1, acc[0][1], 0, 0, 0);
            acc[1][0] = __builtin_amdgcn_mfma_f32_32x32x16_bf16(a1, b0, acc[1][0], 0, 0, 0);
            acc[1][1] = __builtin_amdgcn_mfma_f32_32x32x16_bf16(a1, b1, acc[1][1], 0, 0, 0);
        }
        __builtin_amdgcn_s_setprio(0);
        __builtin_amdgcn_s_barrier();    // all reads of buf `cur` done before restage
        cur ^= 1;
    }

    // ---- kg merge through LDS (aliases staging; loop fully barriered) ----
    // 8 regions x 16 KB (4096 f32). Wave acc = 4 frags x 16 f32 x 64 lanes.
    float* mg = (float*)AsBs;
    #define ACC_W(rid)                                                          \
        do {                                                                    \
            float* rg = mg + (rid) * 4096;                                      \
            _Pragma("unroll")                                                   \
            for (int m = 0; m < 2; ++m)                                         \
                _Pragma("unroll")                                               \
                for (int n = 0; n < 2; ++n)                                     \
                    _Pragma("unroll")                                           \
                    for (int r = 0; r < 16; ++r)                                \
                        rg[((m * 2 + n) * 16 + r) * 64 + lane] = acc[m][n][r];  \
        } while (0)
    #define ACC_R(rid)                                                         \
        do {                                                                   \
            const float* rg = mg + (rid) * 4096;                               \
            _Pragma("unroll")                                                  \
            for (int m = 0; m < 2; ++m)                                        \
                _Pragma("unroll")                                              \
                for (int n = 0; n < 2; ++n)                                    \
                    _Pragma("unroll")                                          \
                    for (int r = 0; r < 16; ++r)                               \
                        acc[m][n][r] += rg[((m * 2 + n) * 16 + r) * 64 + lane];\
        } while (0)

    __syncthreads();                       // staging fully consumed
    if (kg == 1) ACC_W(wq * 2 + 0);
    if (kg == 3) ACC_W(wq * 2 + 1);
    __syncthreads();
    if (kg == 0) ACC_R(wq * 2 + 0);
    if (kg == 2) ACC_R(wq * 2 + 1);
    __syncthreads();
    if (kg == 2) ACC_W(wq);
    __syncthreads();
    if (kg == 0) {
        ACC_R(wq);
        #pragma unroll
        for (int n = 0; n < 2; ++n) {
            int col = bn0 + wc * 64 + n * 32 + lane31;
            float sc = scale[col];
            float bs = bias[col];
            #pragma unroll
            for (int m = 0; m < 2; ++m) {
                int rowbase = bm0 + wr * 64 + m * 32 + 4 * khalf;
                #pragma unroll
                for (int r = 0; r < 16; ++r) {
                    int row = rowbase + (r & 3) + 8 * (r >> 2);
                    C[(size_t)row * N + col] = acc[m][n][r] * sc + bs;
                }
            }
        }
    }
    #undef ACC_W
    #undef ACC_R
    #undef STAGE
    #undef AS
    #undef BS
}

extern "C" void kernel_launch(void* const* d_in, const int* in_sizes, int n_in,
                              void* d_out, int out_size, void* d_ws, size_t ws_size,
                              hipStream_t stream)
{
    const float* x    = (const float*)d_in[0];
    const float* w    = (const float*)d_in[1];
    const float* bias = (const float*)d_in[2];
    float* out = (float*)d_out;

    const int OUT = in_sizes[2];            // 1024
    const int IN  = in_sizes[1] / OUT;      // 4096
    const int B   = in_sizes[0] / IN;       // 4096

    // workspace layout: x_bf16 [B*IN] | w_tern_bf16 [OUT*IN] | scale [OUT]
    unsigned short* Xb = (unsigned short*)d_ws;
    unsigned short* Wq = Xb + (size_t)B * IN;
    float* scale = (float*)(Wq + (size_t)OUT * IN);

    quant_tern<<<OUT, 256, 0, stream>>>(w, Wq, scale, IN);
    cast_x<<<2048, 256, 0, stream>>>(x, Xb, (B * IN) / 8, IN / 8);
    gemm_tern<<<dim3((B / BM) * (OUT / BN)), THREADS, 0, stream>>>(
        Xb, Wq, scale, bias, out, B, OUT, IN);
}